// Round 8
// baseline (7041.005 us; speedup 1.0000x reference)
//
#include <hip/hip_runtime.h>
#include <cstdint>

constexpr int BB = 128;   // batch
constexpr int SS = 512;   // source length
constexpr int DD = 512;   // hidden dim
constexpr int TT = 64;    // decode steps
constexpr int OO = 3;     // output dim

typedef __attribute__((ext_vector_type(8))) short bf16x8;
typedef __attribute__((ext_vector_type(4))) float f32x4;

__device__ __forceinline__ float tanh_fast(float x) {
  float e = __expf(2.0f * x);
  return 1.0f - 2.0f / (e + 1.0f);
}
__device__ __forceinline__ float sigmoid_fast(float x) {
  return 1.0f / (1.0f + __expf(-x));
}
__device__ __forceinline__ unsigned short f2bf(float f) {
  uint32_t u = __float_as_uint(f);
  uint32_t r = (u + 0x7FFFu + ((u >> 16) & 1u)) >> 16;  // RNE
  return (unsigned short)r;
}
__device__ __forceinline__ float2 bfx2(uint32_t u) {
  float2 r;
  r.x = __uint_as_float(u << 16);
  r.y = __uint_as_float(u & 0xFFFF0000u);
  return r;
}

// ---------------------------------------------------------------------------
// MFMA bf16 GEMM: Uk = e_bf [65536x512] @ Ua_bf^T [512x512] + bu -> bf16
// (unchanged from R7: 128x128 tile, 4 waves of 4x4 16x16x32 MFMA, pitch-40 LDS)
// ---------------------------------------------------------------------------
__global__ __launch_bounds__(256) void gemm_uk_mfma(
    const unsigned short* __restrict__ A, const unsigned short* __restrict__ Bw,
    const float* __restrict__ bias, unsigned short* __restrict__ Uk) {
  __shared__ unsigned short Asb[128 * 40];
  __shared__ unsigned short Bsb[128 * 40];
  const int tid = threadIdx.x;
  const int m0 = blockIdx.y * 128, n0 = blockIdx.x * 128;
  const int w = tid >> 6, l = tid & 63;
  const int wr = w >> 1, wc = w & 1;
  const int lm = l & 15, kg = l >> 4;

  f32x4 acc[4][4] = {};

  for (int kc = 0; kc < 512; kc += 32) {
    uint4 av[2], bv[2];
#pragma unroll
    for (int p = 0; p < 2; ++p) {
      int u = tid + p * 256;
      int r = u >> 2, ko = (u & 3) * 8;
      av[p] = *(const uint4*)(A + (size_t)(m0 + r) * 512 + kc + ko);
      bv[p] = *(const uint4*)(Bw + (size_t)(n0 + r) * 512 + kc + ko);
    }
    __syncthreads();
#pragma unroll
    for (int p = 0; p < 2; ++p) {
      int u = tid + p * 256;
      int r = u >> 2, ko = (u & 3) * 8;
      *(uint4*)&Asb[r * 40 + ko] = av[p];
      *(uint4*)&Bsb[r * 40 + ko] = bv[p];
    }
    __syncthreads();
    bf16x8 af[4], bfr[4];
#pragma unroll
    for (int i = 0; i < 4; ++i) {
      af[i]  = *(const bf16x8*)&Asb[(wr * 64 + i * 16 + lm) * 40 + kg * 8];
      bfr[i] = *(const bf16x8*)&Bsb[(wc * 64 + i * 16 + lm) * 40 + kg * 8];
    }
#pragma unroll
    for (int i = 0; i < 4; ++i)
#pragma unroll
      for (int j = 0; j < 4; ++j)
        acc[i][j] = __builtin_amdgcn_mfma_f32_16x16x32_bf16(af[i], bfr[j],
                                                            acc[i][j], 0, 0, 0);
  }

  const int row_base = m0 + wr * 64;
  const int col_base = n0 + wc * 64;
#pragma unroll
  for (int j = 0; j < 4; ++j) {
    const int col = col_base + j * 16 + lm;
    const float bu = bias[col];
#pragma unroll
    for (int i = 0; i < 4; ++i) {
      const int r0 = row_base + i * 16 + kg * 4;
#pragma unroll
      for (int rr = 0; rr < 4; ++rr)
        Uk[(size_t)(r0 + rr) * 512 + col] = f2bf(acc[i][j][rr] + bu);
    }
  }
}

// fp32 -> bf16, 8 elems/thread
__global__ __launch_bounds__(256) void conv_bf(const float* __restrict__ in,
                                               unsigned short* __restrict__ outp) {
  size_t idx = ((size_t)blockIdx.x * 256 + threadIdx.x) * 8;
  const float4* p = (const float4*)(in + idx);
  float4 a = p[0], b = p[1];
  uint4 r;
  r.x = f2bf(a.x) | ((uint32_t)f2bf(a.y) << 16);
  r.y = f2bf(a.z) | ((uint32_t)f2bf(a.w) << 16);
  r.z = f2bf(b.x) | ((uint32_t)f2bf(b.y) << 16);
  r.w = f2bf(b.z) | ((uint32_t)f2bf(b.w) << 16);
  *(uint4*)(outp + idx) = r;
}

// Wcat packed uint32[512 k][1024 col-pairs]: pairs 0..255 -> Wa cols (q),
// pairs 256..1023 -> W_hh cols (gh)
__global__ void prep_wcat(const float* __restrict__ Wa,
                          const float* __restrict__ Whh,
                          uint32_t* __restrict__ Wcat) {
  int idx = blockIdx.x * 256 + threadIdx.x;  // 512*1024
  int k = idx >> 10, j2 = idx & 1023;
  int j0 = 2 * j2;
  float v0 = (j0 < DD) ? Wa[(size_t)j0 * DD + k] : Whh[(size_t)(j0 - DD) * DD + k];
  float v1 = (j0 + 1 < DD) ? Wa[(size_t)(j0 + 1) * DD + k]
                           : Whh[(size_t)(j0 + 1 - DD) * DD + k];
  Wcat[idx] = (uint32_t)f2bf(v0) | ((uint32_t)f2bf(v1) << 16);
}

// WihT packed uint32[512 k][768 col-pairs]: pair pp -> W_ih cols (2pp, 2pp+1)
__global__ void prep_wihT(const float* __restrict__ W_ih,
                          uint32_t* __restrict__ WihT) {
  int idx = blockIdx.x * 256 + threadIdx.x;  // 512*768
  int k = idx / 768, pp = idx % 768;
  int p0 = 2 * pp;
  float v0 = W_ih[(size_t)p0 * (DD + OO) + k];
  float v1 = W_ih[(size_t)(p0 + 1) * (DD + OO) + k];
  WihT[idx] = (uint32_t)f2bf(v0) | ((uint32_t)f2bf(v1) << 16);
}

// ---------------------------------------------------------------------------
// K1: grid (2, B) x 1024 threads.
//  role 0 (blockIdx.x==0): out-proj of h_{t-1} (t>0), q = h@Wa^T+ba (in LDS),
//     scores = va.tanh(q+Uk)+vb, exact softmax, ctx = w.e_bf, attn_out.
//  role 1: gh = h@W_hh^T + b_hh  (bf16 Wcat cols 512..2047).
// h is read-only here (written by K2).
// ---------------------------------------------------------------------------
__global__ __launch_bounds__(1024) void step_k1(
    const unsigned short* __restrict__ Uk_bf,
    const unsigned short* __restrict__ e_bf,
    const uint32_t* __restrict__ Wcat,
    const float* __restrict__ ba, const float* __restrict__ bhh,
    const float* __restrict__ va, const float* __restrict__ vb_p,
    const float* __restrict__ W_out, const float* __restrict__ b_out,
    const float* __restrict__ h,
    float* __restrict__ ctx, float* __restrict__ gh,
    float* __restrict__ out_d, float* __restrict__ out_attn, int t) {
  const int b = blockIdx.y;
  const int tid = threadIdx.x;

  __shared__ float hs[DD];
  __shared__ __align__(16) float qsh[DD];
  __shared__ __align__(16) float vash[DD];
  __shared__ float w[SS];
  __shared__ float red[16];
  __shared__ float2 qp[4][256];
  __shared__ float part[16][520];

  if (tid < DD) hs[tid] = h[(size_t)b * DD + tid];
  __syncthreads();

  if (blockIdx.x == 1) {
    // ---- gh block: 768 active threads, one col-pair each
    if (tid < 768) {
      const int j2 = 256 + tid;
      float2 acc = {0.f, 0.f};
#pragma unroll 8
      for (int k = 0; k < DD; ++k) {
        float2 wv = bfx2(Wcat[(size_t)k * 1024 + j2]);
        float hv = hs[k];
        acc.x += hv * wv.x;
        acc.y += hv * wv.y;
      }
      const int j0 = 2 * tid;
      gh[(size_t)b * 3 * DD + j0] = acc.x + bhh[j0];
      gh[(size_t)b * 3 * DD + j0 + 1] = acc.y + bhh[j0 + 1];
    }
    return;
  }

  const int wid = tid >> 6, lane = tid & 63;

  // ---- out-proj of previous step's h (h currently holds h_{t-1})
  if (t > 0 && wid < OO) {
    const float* wrow = W_out + (size_t)wid * DD;
    float acc = 0.f;
    for (int i = lane; i < DD; i += 64) acc += hs[i] * wrow[i];
#pragma unroll
    for (int off = 32; off; off >>= 1) acc += __shfl_xor(acc, off);
    if (lane == 0) out_d[((size_t)b * TT + (t - 1)) * OO + wid] = acc + b_out[wid];
  }
  if (tid < DD) vash[tid] = va[tid];

  // ---- q = h @ Wa^T + ba : threads (kh=tid>>8, e2=tid&255), k-quarters
  {
    const int kh = tid >> 8, e2 = tid & 255;
    float2 acc = {0.f, 0.f};
    for (int k = kh * 128; k < kh * 128 + 128; ++k) {
      float2 wv = bfx2(Wcat[(size_t)k * 1024 + e2]);
      float hv = hs[k];
      acc.x += hv * wv.x;
      acc.y += hv * wv.y;
    }
    qp[kh][e2] = acc;
  }
  __syncthreads();
  if (tid < 256) {
    float2 r0 = qp[0][tid], r1 = qp[1][tid], r2 = qp[2][tid], r3 = qp[3][tid];
    qsh[2 * tid] = r0.x + r1.x + r2.x + r3.x + ba[2 * tid];
    qsh[2 * tid + 1] = r0.y + r1.y + r2.y + r3.y + ba[2 * tid + 1];
  }
  __syncthreads();

  // ---- scores: 16 lanes per s-row, 64 rows/pass, 8 passes; uint4 Uk loads
  {
    const float vb = vb_p[0];
    const int g = tid >> 4, l = tid & 15;
    const float4* q4 = (const float4*)qsh;
    const float4* v4 = (const float4*)vash;
#pragma unroll
    for (int i = 0; i < 8; ++i) {
      const int s = g + 64 * i;
      const uint4* row = (const uint4*)(Uk_bf + ((size_t)b * SS + s) * DD);
      float acc = 0.f;
#pragma unroll
      for (int jj = 0; jj < 4; ++jj) {
        const int slot = l + 16 * jj;
        uint4 u = row[slot];
        float4 q0 = q4[slot * 2], q1 = q4[slot * 2 + 1];
        float4 v0 = v4[slot * 2], v1 = v4[slot * 2 + 1];
        float2 e0 = bfx2(u.x), e1 = bfx2(u.y), e2 = bfx2(u.z), e3 = bfx2(u.w);
        acc += v0.x * tanh_fast(q0.x + e0.x);
        acc += v0.y * tanh_fast(q0.y + e0.y);
        acc += v0.z * tanh_fast(q0.z + e1.x);
        acc += v0.w * tanh_fast(q0.w + e1.y);
        acc += v1.x * tanh_fast(q1.x + e2.x);
        acc += v1.y * tanh_fast(q1.y + e2.y);
        acc += v1.z * tanh_fast(q1.z + e3.x);
        acc += v1.w * tanh_fast(q1.w + e3.y);
      }
#pragma unroll
      for (int off = 8; off; off >>= 1) acc += __shfl_down(acc, off, 16);
      if (l == 0) w[s] = acc + vb;
    }
  }
  __syncthreads();

  // ---- softmax over w[0..511]
  float v = (tid < SS) ? w[tid] : -3.4e38f;
  float m = v;
#pragma unroll
  for (int off = 32; off; off >>= 1) m = fmaxf(m, __shfl_xor(m, off));
  if (lane == 0) red[wid] = m;
  __syncthreads();
  if (tid < 16) {
    float mm = red[tid];
#pragma unroll
    for (int off = 8; off; off >>= 1) mm = fmaxf(mm, __shfl_xor(mm, off, 16));
    red[tid] = mm;
  }
  __syncthreads();
  m = red[0];
  float e_ = (tid < SS) ? __expf(v - m) : 0.f;
  float ssum = e_;
#pragma unroll
  for (int off = 32; off; off >>= 1) ssum += __shfl_xor(ssum, off);
  __syncthreads();
  if (lane == 0) red[wid] = ssum;
  __syncthreads();
  if (tid < 16) {
    float s2 = red[tid];
#pragma unroll
    for (int off = 8; off; off >>= 1) s2 += __shfl_xor(s2, off, 16);
    red[tid] = s2;
  }
  __syncthreads();
  const float inv = 1.f / red[0];
  if (tid < SS) {
    float wv = e_ * inv;
    w[tid] = wv;
    out_attn[((size_t)b * TT + t) * SS + tid] = wv;
  }
  __syncthreads();

  // ---- ctx: threads (ss=tid>>6 in [0,16), slot=tid&63): 8 cols, 32 s-rows
  {
    const int ss = tid >> 6, slot = tid & 63;
    const unsigned short* eb = e_bf + (size_t)b * SS * DD + slot * 8;
    float a0 = 0.f, a1 = 0.f, a2 = 0.f, a3 = 0.f;
    float a4 = 0.f, a5 = 0.f, a6 = 0.f, a7 = 0.f;
    for (int s = ss * 32; s < ss * 32 + 32; ++s) {
      uint4 u = *(const uint4*)(eb + (size_t)s * DD);
      float ws = w[s];
      float2 p0 = bfx2(u.x), p1 = bfx2(u.y), p2 = bfx2(u.z), p3 = bfx2(u.w);
      a0 += ws * p0.x; a1 += ws * p0.y;
      a2 += ws * p1.x; a3 += ws * p1.y;
      a4 += ws * p2.x; a5 += ws * p2.y;
      a6 += ws * p3.x; a7 += ws * p3.y;
    }
    float* pr = &part[ss][slot * 8];
    pr[0] = a0; pr[1] = a1; pr[2] = a2; pr[3] = a3;
    pr[4] = a4; pr[5] = a5; pr[6] = a6; pr[7] = a7;
  }
  __syncthreads();
  if (tid < DD) {
    float r = 0.f;
#pragma unroll
    for (int ss = 0; ss < 16; ++ss) r += part[ss][tid];
    ctx[(size_t)b * DD + tid] = r;
  }
}

// ---------------------------------------------------------------------------
// K2: grid (2, B) x 1024 threads. Block (half, b): gi for its 768 cols
// (3 gates x 256 d-range) from bf16 WihT + x-cols, then GRU elementwise
// update of d in [half*256, half*256+256). gi never hits global.
// ---------------------------------------------------------------------------
__global__ __launch_bounds__(1024) void step_k2(
    const float* __restrict__ ctx, const uint32_t* __restrict__ WihT,
    const float* __restrict__ W_ih, const float* __restrict__ bih,
    const float* __restrict__ target, const float* __restrict__ gh,
    float* __restrict__ h, int t) {
  const int half = blockIdx.x, b = blockIdx.y;
  const int tid = threadIdx.x;
  __shared__ float cs[DD];
  __shared__ float gis[768];
  __shared__ float xs[3];

  if (tid < DD) cs[tid] = ctx[(size_t)b * DD + tid];
  if (tid < 3) xs[tid] = (t > 0) ? target[((size_t)b * TT + (t - 1)) * OO + tid] : 0.f;
  __syncthreads();

  if (tid < 384) {
    const int gate = tid >> 7, pi = tid & 127;
    const int ppair = gate * 256 + half * 128 + pi;   // WihT pair index
    const int p0 = 2 * ppair;                          // physical gi col
    float2 acc = {0.f, 0.f};
#pragma unroll 8
    for (int k = 0; k < DD; ++k) {
      float2 wv = bfx2(WihT[(size_t)k * 768 + ppair]);
      float cv = cs[k];
      acc.x += cv * wv.x;
      acc.y += cv * wv.y;
    }
    const float* wx0 = W_ih + (size_t)p0 * (DD + OO) + DD;
    const float* wx1 = W_ih + (size_t)(p0 + 1) * (DD + OO) + DD;
    acc.x += xs[0] * wx0[0] + xs[1] * wx0[1] + xs[2] * wx0[2];
    acc.y += xs[0] * wx1[0] + xs[1] * wx1[1] + xs[2] * wx1[2];
    const int l0 = gate * 256 + 2 * pi;
    gis[l0] = acc.x + bih[p0];
    gis[l0 + 1] = acc.y + bih[p0 + 1];
  }
  __syncthreads();

  if (tid < 256) {
    const int d = half * 256 + tid;
    const float* ghb = gh + (size_t)b * 3 * DD;
    float ir = gis[tid], iz = gis[256 + tid], in_ = gis[512 + tid];
    float r = sigmoid_fast(ir + ghb[d]);
    float z = sigmoid_fast(iz + ghb[DD + d]);
    float n = tanh_fast(in_ + r * ghb[2 * DD + d]);
    float hp = h[(size_t)b * DD + d];
    h[(size_t)b * DD + d] = (1.f - z) * n + z * hp;
  }
}

// tail: out_d[:,T-1] = h@W_out^T + b_out ; out_hT = h
__global__ __launch_bounds__(512) void out_tail(
    const float* __restrict__ h, const float* __restrict__ W_out,
    const float* __restrict__ b_out, float* __restrict__ out_d,
    float* __restrict__ out_hT) {
  const int b = blockIdx.x, tid = threadIdx.x;
  __shared__ float hs[DD];
  float hv = h[(size_t)b * DD + tid];
  hs[tid] = hv;
  out_hT[(size_t)b * DD + tid] = hv;
  __syncthreads();
  const int wid = tid >> 6, lane = tid & 63;
  if (wid < OO) {
    const float* wrow = W_out + (size_t)wid * DD;
    float acc = 0.f;
    for (int i = lane; i < DD; i += 64) acc += hs[i] * wrow[i];
#pragma unroll
    for (int off = 32; off; off >>= 1) acc += __shfl_xor(acc, off);
    if (lane == 0) out_d[((size_t)b * TT + (TT - 1)) * OO + wid] = acc + b_out[wid];
  }
}

// ---------------------------------------------------------------------------
extern "C" void kernel_launch(void* const* d_in, const int* in_sizes, int n_in,
                              void* d_out, int out_size, void* d_ws, size_t ws_size,
                              hipStream_t stream) {
  const float* e_all  = (const float*)d_in[0];
  const float* e_last = (const float*)d_in[1];
  const float* target = (const float*)d_in[2];
  const float* Wa     = (const float*)d_in[3];
  const float* ba     = (const float*)d_in[4];
  const float* Ua     = (const float*)d_in[5];
  const float* bu     = (const float*)d_in[6];
  const float* Va_w   = (const float*)d_in[7];
  const float* Va_b   = (const float*)d_in[8];
  const float* W_ih   = (const float*)d_in[9];
  const float* b_ih   = (const float*)d_in[10];
  const float* W_hh   = (const float*)d_in[11];
  const float* b_hh   = (const float*)d_in[12];
  const float* W_out  = (const float*)d_in[13];
  const float* b_out  = (const float*)d_in[14];

  float* out      = (float*)d_out;
  float* out_d    = out;                         // [B,T,3]
  float* out_hT   = out + (size_t)BB * TT * OO;  // [1,B,D]
  float* out_attn = out_hT + (size_t)BB * DD;    // [B,T,S]

  // Workspace: 139,198,464 B < 139,479,040 B (R1-proven safe size).
  // WihT overlays the Ua_bf slot (prep_wihT launched after gemm_uk_mfma;
  // stream ordering makes the overlap safe).
  char* wsB = (char*)d_ws;
  unsigned short* Uk_bf = (unsigned short*)wsB;                               // 67.11 MB
  unsigned short* e_bf  = (unsigned short*)(wsB + (size_t)BB * SS * DD * 2);  // 67.11 MB
  uint32_t* Wcat = (uint32_t*)(wsB + (size_t)BB * SS * DD * 4);               // 2.10 MB
  char* overlap = wsB + (size_t)BB * SS * DD * 4 + (size_t)DD * 1024 * 4;     // 1.57 MB
  unsigned short* Ua_bf = (unsigned short*)overlap;       // 0.52 MB (preamble only)
  uint32_t* WihT = (uint32_t*)overlap;                    // 1.57 MB (loop)
  float* fws = (float*)(overlap + (size_t)DD * 768 * 4);
  float* h   = fws;                               // B*D
  float* ctx = h + (size_t)BB * DD;               // B*D
  float* gh  = ctx + (size_t)BB * DD;             // B*3D

  conv_bf<<<(BB * SS * DD) / (8 * 256), 256, 0, stream>>>(e_all, e_bf);
  conv_bf<<<(DD * DD) / (8 * 256), 256, 0, stream>>>(Ua, Ua_bf);
  prep_wcat<<<(DD * 1024) / 256, 256, 0, stream>>>(Wa, W_hh, Wcat);
  gemm_uk_mfma<<<dim3(DD / 128, (BB * SS) / 128), 256, 0, stream>>>(
      e_bf, Ua_bf, bu, Uk_bf);
  prep_wihT<<<(DD * 768) / 256, 256, 0, stream>>>(W_ih, WihT);  // overwrites Ua_bf
  hipMemcpyAsync(h, e_last, (size_t)BB * DD * sizeof(float),
                 hipMemcpyDeviceToDevice, stream);

  for (int t = 0; t < TT; ++t) {
    step_k1<<<dim3(2, BB), 1024, 0, stream>>>(
        Uk_bf, e_bf, Wcat, ba, b_hh, Va_w, Va_b, W_out, b_out,
        h, ctx, gh, out_d, out_attn, t);
    step_k2<<<dim3(2, BB), 1024, 0, stream>>>(
        ctx, WihT, W_ih, b_ih, target, gh, h, t);
  }
  out_tail<<<BB, 512, 0, stream>>>(h, W_out, b_out, out_d, out_hT);
}